// Round 16
// baseline (534.928 us; speedup 1.0000x reference)
//
#include <hip/hip_runtime.h>
#include <math.h>

typedef _Float16 f16;
typedef __attribute__((ext_vector_type(8))) _Float16 f16x8;
typedef __attribute__((ext_vector_type(16))) float f32x16;

union U64x2 { unsigned long long u[2]; f16x8 v; };
union Q16   { uint4 q; unsigned long long u[2]; };

constexpr int ilog2c(int x) { return x <= 1 ? 0 : 1 + ilog2c(x >> 1); }

__device__ __forceinline__ float fast_tanh(float x) {
    float e = __expf(2.f * x);
    return (e - 1.f) / (e + 1.f);
}

// Fenced raw barrier: LDS-safe, does NOT drain vmcnt.
__device__ __forceinline__ void barrier_no_vmdrain() {
    asm volatile("s_waitcnt lgkmcnt(0)" ::: "memory");
    __builtin_amdgcn_sched_barrier(0);
    __builtin_amdgcn_s_barrier();
    __builtin_amdgcn_sched_barrier(0);
}

// ===========================================================================
// fp16 MFMA implicit-GEMM conv/deconv (k4 s2 p1), NHWC activations.
// Round-26 = round-15 (verified 521.9us) + deconv3 HALO-staged: 4 phases
// (seg x t2h), each stages ONE 16x18 halo band and runs all 4 (pw,t2w)
// combos; dw by read addressing. mfma_conv/conv1/deconv4/BN unchanged.
// ===========================================================================
template<int CIN,int IH,int IW,int OH,int OW,int COUT,int COB,int SPT,int KS,
         int CO_FR,bool DEC,bool PAIR>
__global__ __launch_bounds__(256,2) void mfma_conv(
    const f16* __restrict__ xin, const f16* __restrict__ wp,
    f16* __restrict__ out16, float* __restrict__ out32, size_t ps,
    float* __restrict__ psumF, float* __restrict__ psqF)
{
    constexpr int OHo  = DEC ? OH/2 : OH;
    constexpr int OWo  = DEC ? OW/2 : OW;
    constexpr int KTOT = CIN * (DEC ? 4 : 16);
    constexpr int CH   = (KTOT/64) / KS;
    constexpr int RPT  = CIN / 64;
    constexpr int RSH  = (RPT==1?0:RPT==2?1:RPT==4?2:3);
    constexpr int WSTR = CIN * 16;
    constexpr int TPR  = 256 / COB;
    constexpr int SPB  = OHo * OWo;
    constexpr int LSPB = ilog2c(SPB);
    constexpr int LOWo = ilog2c(OWo);

    static_assert(!PAIR || (RPT >= 2 && CH % 2 == 0), "PAIR needs RPT>=2");
    constexpr int CHU  = PAIR ? CH/2 : CH;      // outer chunk count
    constexpr int RW   = PAIR ? 32 : 16;        // ull per LDS row
    constexpr int PM   = PAIR ? 15 : 7;         // pair-swizzle mask
    constexpr int KKN  = PAIR ? 8 : 4;          // kk steps per chunk
    constexpr int XU4  = PAIR ? 16 : 8;         // uint4/thread X
    constexpr int WSEG = (PAIR ? 128 : 64)/TPR; // f16/thread W
    constexpr int WU4  = WSEG / 8;              // uint4/thread W

    __shared__ unsigned long long Xs[SPT*RW];
    __shared__ unsigned long long Wls[COB*RW];

    const int t   = threadIdx.x;
    const int bx  = blockIdx.x;
    const int cob = blockIdx.y;
    const int bz  = blockIdx.z;
    const int par = DEC ? (bz & 3) : 0;
    const int ks  = DEC ? (bz >> 2) : bz;
    const int poh = par >> 1, pw = par & 1;

    const int gsp_s = bx*SPT + t;
    const int img_s = gsp_s >> LSPB;
    const int r_s   = gsp_s & (SPB-1);
    const int oy_s  = r_s >> LOWo;
    const int ox_s  = r_s & (OWo-1);

    const int wco   = t / TPR;
    const int wpart = t % TPR;
    const f16* wbase = wp + (size_t)(cob*COB + wco)*WSTR + wpart*WSEG;

    const int wave = t >> 6, lane = t & 63, half = lane >> 5, l31 = lane & 31;
    const int co_w = (wave >> 1) * (CO_FR*32);
    const int sp_w = (wave & 1) * 128;
    const int swz  = l31 & PM;   // row&PM for every row this lane reads

    f32x16 acc[CO_FR][4];
    #pragma unroll
    for (int i = 0; i < CO_FR; ++i)
        #pragma unroll
        for (int b = 0; b < 4; ++b)
            #pragma unroll
            for (int r = 0; r < 16; ++r) acc[i][b][r] = 0.f;

    uint4 xreg[XU4];
    uint4 wreg[WU4];

    auto issue = [&](int cc) {
        const int gc  = ks*CH + (PAIR ? 2*cc : cc);
        const int tap = gc >> RSH;
        const int ci0 = (gc & (RPT-1)) << 6;    // PAIR: covers ci0..ci0+127
        int kh, kw, ih, iw;
        if (DEC) {
            const int t2h = tap >> 1, t2w = tap & 1;
            kh = (1-poh) + 2*t2h; kw = (1-pw) + 2*t2w;
            ih = oy_s + poh - t2h; iw = ox_s + pw - t2w;
        } else {
            kh = tap >> 2; kw = tap & 3;
            ih = 2*oy_s - 1 + kh; iw = 2*ox_s - 1 + kw;
        }
        const int woff = (kh*4 + kw)*CIN + ci0;
        const uint4* wsrc = (const uint4*)(wbase + woff);
        #pragma unroll
        for (int j = 0; j < WU4; ++j) wreg[j] = wsrc[j];
        const bool ok = (unsigned)ih < (unsigned)IH && (unsigned)iw < (unsigned)IW;
        if (ok) {
            const uint4* xsrc = (const uint4*)
                (xin + ((size_t)(img_s*IH + ih)*IW + iw)*CIN + ci0);
            #pragma unroll
            for (int j = 0; j < XU4; ++j) xreg[j] = xsrc[j];
        } else {
            #pragma unroll
            for (int j = 0; j < XU4; ++j) xreg[j] = uint4{0u,0u,0u,0u};
        }
    };

    issue(0);

    for (int cc = 0; cc < CHU; ++cc) {
        // LEAD barrier: raw, no vmcnt drain.
        if (cc) barrier_no_vmdrain();

        #pragma unroll
        for (int j = 0; j < WU4; ++j) {
            Q16 v; v.q = wreg[j];
            const int lp = wpart*WU4 + j;
            const int u0 = wco*RW + ((lp ^ (wco & PM)) << 1);
            Wls[u0]   = v.u[0];
            Wls[u0+1] = v.u[1];
        }
        {
            #pragma unroll
            for (int j = 0; j < XU4; ++j) {
                Q16 v; v.q = xreg[j];
                const int u0 = t*RW + ((j ^ (t & PM)) << 1);
                Xs[u0]   = v.u[0];
                Xs[u0+1] = v.u[1];
            }
        }

        // issue NEXT chunk's global loads — in flight across both barriers.
        if (cc + 1 < CHU) issue(cc + 1);

        asm volatile("s_waitcnt lgkmcnt(0)" ::: "memory"); // my ds_writes visible
        __builtin_amdgcn_sched_barrier(0);                 // nothing crosses
        __builtin_amdgcn_s_barrier();                      // NO vmcnt drain
        __builtin_amdgcn_sched_barrier(0);                 // ds_reads stay below

        #pragma unroll
        for (int kk = 0; kk < KKN; ++kk) {
            const int so = ((kk*2 + half) ^ swz) << 1;
            f16x8 wf[CO_FR], xf[4];
            #pragma unroll
            for (int i = 0; i < CO_FR; ++i) {
                U64x2 u; const int rw = (co_w + i*32 + l31)*RW + so;
                u.u[0] = Wls[rw]; u.u[1] = Wls[rw+1]; wf[i] = u.v;
            }
            #pragma unroll
            for (int b = 0; b < 4; ++b) {
                U64x2 u; const int rx = (sp_w + b*32 + l31)*RW + so;
                u.u[0] = Xs[rx]; u.u[1] = Xs[rx+1]; xf[b] = u.v;
            }
            #pragma unroll
            for (int i = 0; i < CO_FR; ++i)
                #pragma unroll
                for (int b = 0; b < 4; ++b)
                    acc[i][b] = __builtin_amdgcn_mfma_f32_32x32x16_f16(
                        xf[b], wf[i], acc[i][b], 0, 0, 0);
        }
    }

    #pragma unroll
    for (int b = 0; b < 4; ++b) {
        #pragma unroll
        for (int q = 0; q < 4; ++q) {
            #pragma unroll
            for (int r2 = 0; r2 < 4; ++r2) {
                const int sp_loc = sp_w + b*32 + q*8 + 4*half + r2;
                const int gsp    = bx*SPT + sp_loc;
                size_t base;
                if (DEC) {
                    const int img = gsp >> LSPB;
                    const int r   = gsp & (SPB-1);
                    const int oh  = 2*(r >> LOWo) + poh;
                    const int ow  = 2*(r & (OWo-1)) + pw;
                    base = ((size_t)(img*OH + oh)*OW + ow)*COUT + cob*COB;
                } else {
                    base = (size_t)gsp*COUT + cob*COB;
                }
                #pragma unroll
                for (int i = 0; i < CO_FR; ++i) {
                    const int co_l = co_w + i*32 + l31;
                    const float v  = acc[i][b][q*4 + r2];
                    if (KS == 1) out16[base + co_l] = (_Float16)v;
                    else         out32[(size_t)ks*ps + base + co_l] = v;
                }
            }
        }
    }

    if (KS == 1 && psumF != nullptr) {
        // per-wave partials
        float sArr[CO_FR], qArr[CO_FR];
        #pragma unroll
        for (int i = 0; i < CO_FR; ++i) {
            float s = 0.f, q = 0.f;
            #pragma unroll
            for (int b = 0; b < 4; ++b)
                #pragma unroll
                for (int r = 0; r < 16; ++r) {
                    const float v = acc[i][b][r];
                    s += v; q += v * v;
                }
            s += __shfl_down(s, 32);
            q += __shfl_down(q, 32);
            sArr[i] = s; qArr[i] = q;
        }
        // block-level LDS reduction: 4 wave-partials -> 1 wave-atomic/array
        __syncthreads();                       // Xs reads complete everywhere
        float* LS = (float*)Xs;                // 4*CO_FR*32 floats
        float* LQ = LS + 4*CO_FR*32;
        if (half == 0) {
            #pragma unroll
            for (int i = 0; i < CO_FR; ++i) {
                LS[(wave*CO_FR + i)*32 + l31] = sArr[i];
                LQ[(wave*CO_FR + i)*32 + l31] = qArr[i];
            }
        }
        __syncthreads();
        if (t < COB) {
            constexpr int KSH = (CO_FR == 1 ? 5 : 6);
            const int k  = t >> KSH;
            const int ii = (CO_FR == 1) ? 0 : ((t >> 5) & 1);
            const int l  = t & 31;
            const int i0 = ((2*k)  *CO_FR + ii)*32 + l;
            const int i1 = ((2*k+1)*CO_FR + ii)*32 + l;
            atomicAdd(psumF + cob*COB + t, LS[i0] + LS[i1]);
            atomicAdd(psqF  + cob*COB + t, LQ[i0] + LQ[i1]);
        }
    }
}

// ---------------------------------------------------------------------------
// conv1 via MFMA + fused BN stats (single stage). Packed+swizzled LDS
// (40,960 B); launch_bounds(256,2). Block-reduced stat atomics.
// ---------------------------------------------------------------------------
__global__ __launch_bounds__(256,2) void conv1_mfma(
    const f16* __restrict__ xp, const f16* __restrict__ wp,
    f16* __restrict__ out, float* __restrict__ psumF, float* __restrict__ psqF)
{
    __shared__ unsigned long long Xs[256*16];
    __shared__ unsigned long long Wls[64*16];
    const int t = threadIdx.x, bx = blockIdx.x;

    {
        const int r = t >> 2, part = t & 3;
        const uint4* src = (const uint4*)(wp + r*64 + part*16);
        Q16 v0; v0.q = src[0];
        Q16 v1; v1.q = src[1];
        const int a0 = r*16 + (((part*2)   ^ (r & 7)) << 1);
        const int a1 = r*16 + (((part*2+1) ^ (r & 7)) << 1);
        Wls[a0]   = v0.u[0]; Wls[a0+1] = v0.u[1];
        Wls[a1]   = v1.u[0]; Wls[a1+1] = v1.u[1];
    }
    {
        const int gsp = bx*256 + t;
        const int n = gsp >> 10, r = gsp & 1023;
        const int oy = r >> 5, ox = r & 31;
        const int ih0 = 2*oy - 1, iw0 = 2*ox - 1;
        #pragma unroll
        for (int tap = 0; tap < 16; ++tap) {
            const int ih = ih0 + (tap >> 2), iw = iw0 + (tap & 3);
            unsigned long long v = 0ull;
            if ((unsigned)ih < 64u && (unsigned)iw < 64u)
                v = *(const unsigned long long*)(xp + (((size_t)n*64 + ih)*64 + iw)*4);
            const int u = t*16 + (((tap >> 1) ^ (t & 7)) << 1) + (tap & 1);
            Xs[u] = v;
        }
    }
    __syncthreads();

    const int wave = t >> 6, lane = t & 63, half = lane >> 5, l31 = lane & 31;
    const int co_w = (wave >> 1) * 32;
    const int sp_w = (wave & 1) * 128;
    const int swz  = l31 & 7;

    f32x16 acc[4];
    #pragma unroll
    for (int b = 0; b < 4; ++b)
        #pragma unroll
        for (int r = 0; r < 16; ++r) acc[b][r] = 0.f;

    #pragma unroll
    for (int kk = 0; kk < 4; ++kk) {
        const int so = ((kk*2 + half) ^ swz) << 1;
        U64x2 uw; const int rw = (co_w + l31)*16 + so;
        uw.u[0] = Wls[rw]; uw.u[1] = Wls[rw+1];
        #pragma unroll
        for (int b = 0; b < 4; ++b) {
            U64x2 ux; const int rx = (sp_w + b*32 + l31)*16 + so;
            ux.u[0] = Xs[rx]; ux.u[1] = Xs[rx+1];
            acc[b] = __builtin_amdgcn_mfma_f32_32x32x16_f16(
                ux.v, uw.v, acc[b], 0, 0, 0);
        }
    }
    #pragma unroll
    for (int b = 0; b < 4; ++b)
        #pragma unroll
        for (int q = 0; q < 4; ++q)
            #pragma unroll
            for (int r2 = 0; r2 < 4; ++r2) {
                const int sp_loc = sp_w + b*32 + q*8 + 4*half + r2;
                out[(size_t)(bx*256 + sp_loc)*64 + co_w + l31] =
                    (_Float16)acc[b][q*4 + r2];
            }

    float s = 0.f, q = 0.f;
    #pragma unroll
    for (int b = 0; b < 4; ++b)
        #pragma unroll
        for (int r = 0; r < 16; ++r) {
            const float v = acc[b][r];
            s += v; q += v * v;
        }
    s += __shfl_down(s, 32);
    q += __shfl_down(q, 32);
    __syncthreads();                       // Xs reads complete everywhere
    {
        float* LS = (float*)Xs;            // 4*32 floats
        float* LQ = LS + 128;
        if (half == 0) {
            LS[wave*32 + l31] = s;
            LQ[wave*32 + l31] = q;
        }
        __syncthreads();
        if (t < 64) {
            const int k = t >> 5, l = t & 31;
            atomicAdd(psumF + t, LS[(2*k)*32 + l] + LS[(2*k+1)*32 + l]);
            atomicAdd(psqF  + t, LQ[(2*k)*32 + l] + LQ[(2*k+1)*32 + l]);
        }
    }
}

// ---------------------------------------------------------------------------
// deconv3 (128->64, 16x16 -> 32x32) HALO-staged pw-fold (round 26).
// Grid (256, 2): bx = image (block covers the whole 16x16 image), by = poh.
// 4 phases (seg x t2h). Each phase stages ONE 16x18 col-halo band (288
// 128B-units: unit t per thread + 32 tail half-units over threads t<64) and
// the 4 W tap-blocks of (pw,t2w); all 4 combos then run against the band
// with dw resolved by read addressing (col = ox+dw+1, col-XOR swizzle).
// Staging units 3072 -> 1152, barriers 12 -> 4, MFMA unchanged (256).
// LDS 36,864(X) + 32,768(W) = 69,632 B -> 2 blocks/CU. acc[2][4].
// ---------------------------------------------------------------------------
static constexpr int D3P[4]  = {0, 0, 1, 1};   // pw of combo
static constexpr int D3DW[4] = {0,-1, 1, 0};   // dw = pw - t2w
static constexpr int D3KW[4] = {1, 3, 0, 2};   // kw = (1-pw)+2*t2w

__global__ __launch_bounds__(256,2) void deconv3_pwf(
    const f16* __restrict__ xin, const f16* __restrict__ wp,
    f16* __restrict__ out, float* __restrict__ psumF, float* __restrict__ psqF)
{
    __shared__ unsigned long long Xs[288*16];     // 36,864 B (16 rows x 18 cols)
    __shared__ unsigned long long Wls[4][64*16];  // 32,768 B (4 taps)

    const int t   = threadIdx.x;
    const int img = blockIdx.x;                   // one block = one image
    const int poh = blockIdx.y;

    const int rowA = t / 18, colA = t % 18;       // main unit = t
    const int u2   = 256 + (t >> 1);              // tail unit (threads t<64)
    const int row2 = u2 / 18, col2 = u2 % 18;
    const int jh   = (t & 1) * 4;                 // tail slot half (uint4s)

    const int wco   = t >> 2;                     // TPR=4 (COB=64)
    const int wpart = t & 3;
    const f16* wbase = wp + (size_t)wco*2048 + wpart*16;   // WSTR=128*16

    const int wave = t >> 6, lane = t & 63, half = lane >> 5, l31 = lane & 31;
    const int co_w = (wave >> 1) * 32;
    const int sp_w = (wave & 1) * 128;
    const int swz  = l31 & 7;

    f32x16 acc[2][4];   // [pw][sp-block]
    #pragma unroll
    for (int p = 0; p < 2; ++p)
        #pragma unroll
        for (int b = 0; b < 4; ++b)
            #pragma unroll
            for (int r = 0; r < 16; ++r) acc[p][b][r] = 0.f;

    uint4 xreg[8];
    uint4 xregT[4];

    // phase ph: seg = ph>>1, t2h = ph&1, dh = poh - t2h.
    auto issueX = [&](int ph) {
        const int seg = ph >> 1;
        const int dh  = poh - (ph & 1);
        const int ci0 = seg << 6;
        {
            const int iy = rowA + dh, ix = colA - 1;
            const bool ok = (unsigned)iy < 16u && (unsigned)ix < 16u;
            if (ok) {
                const uint4* s = (const uint4*)
                    (xin + ((size_t)(img*16 + iy)*16 + ix)*128 + ci0);
                #pragma unroll
                for (int j = 0; j < 8; ++j) xreg[j] = s[j];
            } else {
                #pragma unroll
                for (int j = 0; j < 8; ++j) xreg[j] = uint4{0u,0u,0u,0u};
            }
        }
        if (t < 64) {
            const int iy = row2 + dh, ix = col2 - 1;
            const bool ok = (unsigned)iy < 16u && (unsigned)ix < 16u;
            if (ok) {
                const uint4* s = (const uint4*)
                    (xin + ((size_t)(img*16 + iy)*16 + ix)*128 + ci0 + jh*8);
                #pragma unroll
                for (int j = 0; j < 4; ++j) xregT[j] = s[j];
            } else {
                #pragma unroll
                for (int j = 0; j < 4; ++j) xregT[j] = uint4{0u,0u,0u,0u};
            }
        }
    };

    issueX(0);

    for (int ph = 0; ph < 4; ++ph) {
        const int seg = ph >> 1;
        const int t2h = ph & 1;
        const int kh  = (1 - poh) + 2*t2h;
        const int ci0 = seg << 6;

        if (ph) barrier_no_vmdrain();

        // W loads for the 4 taps of this (seg, t2h)
        uint4 wregc[4][2];
        #pragma unroll
        for (int i = 0; i < 4; ++i) {
            const uint4* ws = (const uint4*)(wbase + (kh*4 + D3KW[i])*128 + ci0);
            wregc[i][0] = ws[0];
            wregc[i][1] = ws[1];
        }

        // stage X halo band (main + tail)
        {
            const int c7 = colA & 7;
            #pragma unroll
            for (int j = 0; j < 8; ++j) {
                Q16 v; v.q = xreg[j];
                const int u0 = t*16 + ((j ^ c7) << 1);
                Xs[u0]   = v.u[0];
                Xs[u0+1] = v.u[1];
            }
        }
        if (t < 64) {
            const int c72 = col2 & 7;
            #pragma unroll
            for (int j = 0; j < 4; ++j) {
                Q16 v; v.q = xregT[j];
                const int sj = jh + j;
                const int u0 = u2*16 + ((sj ^ c72) << 1);
                Xs[u0]   = v.u[0];
                Xs[u0+1] = v.u[1];
            }
        }
        // stage W taps
        #pragma unroll
        for (int i = 0; i < 4; ++i) {
            #pragma unroll
            for (int j = 0; j < 2; ++j) {
                Q16 v; v.q = wregc[i][j];
                const int lp = wpart*2 + j;
                const int u0 = wco*16 + ((lp ^ (wco & 7)) << 1);
                Wls[i][u0]   = v.u[0];
                Wls[i][u0+1] = v.u[1];
            }
        }

        if (ph + 1 < 4) issueX(ph + 1);

        asm volatile("s_waitcnt lgkmcnt(0)" ::: "memory");
        __builtin_amdgcn_sched_barrier(0);
        __builtin_amdgcn_s_barrier();
        __builtin_amdgcn_sched_barrier(0);

        // all 4 (pw,t2w) combos against the band; dw by addressing
        #pragma unroll
        for (int i = 0; i < 4; ++i) {
            const int p  = D3P[i];
            const int dw = D3DW[i];
            #pragma unroll
            for (int kk = 0; kk < 4; ++kk) {
                const int sW = ((kk*2 + half) ^ swz) << 1;
                U64x2 uw; const int rw = (co_w + l31)*16 + sW;
                uw.u[0] = Wls[i][rw]; uw.u[1] = Wls[i][rw+1];
                #pragma unroll
                for (int b = 0; b < 4; ++b) {
                    const int sp   = sp_w + b*32 + l31;
                    const int row  = sp >> 4;
                    const int colx = (sp & 15) + dw + 1;
                    const int unit = row*18 + colx;
                    const int sX   = ((kk*2 + half) ^ (colx & 7)) << 1;
                    U64x2 ux; const int rx = unit*16 + sX;
                    ux.u[0] = Xs[rx]; ux.u[1] = Xs[rx+1];
                    acc[p][b] = __builtin_amdgcn_mfma_f32_32x32x16_f16(
                        ux.v, uw.v, acc[p][b], 0, 0, 0);
                }
            }
        }
    }

    #pragma unroll
    for (int p = 0; p < 2; ++p) {
        #pragma unroll
        for (int b = 0; b < 4; ++b) {
            #pragma unroll
            for (int q = 0; q < 4; ++q) {
                #pragma unroll
                for (int r2 = 0; r2 < 4; ++r2) {
                    const int sp_loc = sp_w + b*32 + q*8 + 4*half + r2;
                    const int oh     = 2*(sp_loc >> 4) + poh;
                    const int ow     = 2*(sp_loc & 15) + p;
                    const size_t base = ((size_t)(img*32 + oh)*32 + ow)*64;
                    out[base + co_w + l31] = (_Float16)acc[p][b][q*4 + r2];
                }
            }
        }
    }

    if (psumF != nullptr) {
        float s = 0.f, q = 0.f;
        #pragma unroll
        for (int p = 0; p < 2; ++p)
            #pragma unroll
            for (int b = 0; b < 4; ++b)
                #pragma unroll
                for (int r = 0; r < 16; ++r) {
                    const float v = acc[p][b][r];
                    s += v; q += v * v;
                }
        s += __shfl_down(s, 32);
        q += __shfl_down(q, 32);
        __syncthreads();                   // Xs reads complete everywhere
        float* LS = (float*)Xs;            // 4*32 floats
        float* LQ = LS + 128;
        if (half == 0) {
            LS[wave*32 + l31] = s;
            LQ[wave*32 + l31] = q;
        }
        __syncthreads();
        if (t < 64) {
            const int k = t >> 5, l = t & 31;
            atomicAdd(psumF + t, LS[(2*k)*32 + l] + LS[(2*k+1)*32 + l]);
            atomicAdd(psqF  + t, LQ[(2*k)*32 + l] + LQ[(2*k+1)*32 + l]);
        }
    }
}

// ---------------------------------------------------------------------------
// deconv4 (64->3) via MFMA, COUT padded to 32. HALO-staged (round 25,
// verified): 3 dh-phases, acc[4][2], grid 1024. LDS 67,584 B.
// ---------------------------------------------------------------------------
static constexpr int D4P0[4] = {0,0,1,1};
static constexpr int D4KH0[4]= {3,3,3,3};
static constexpr int D4KW0[4]= {3,1,2,0};
static constexpr int D4DW0[4]= {-1,0,0,1};
static constexpr int D4P1[8] = {0,0,1,1,2,2,3,3};
static constexpr int D4KH1[8]= {1,1,1,1,2,2,2,2};
static constexpr int D4KW1[8]= {3,1,2,0,3,1,2,0};
static constexpr int D4DW1[8]= {-1,0,0,1,-1,0,0,1};
static constexpr int D4P2[4] = {2,2,3,3};
static constexpr int D4KH2[4]= {0,0,0,0};
static constexpr int D4KW2[4]= {3,1,2,0};
static constexpr int D4DW2[4]= {-1,0,0,1};

#define D4_PHASE(DH, PA, KHA, KWA, DWA, NC, LEAD, HASNEXT, NEXTDH)           \
    {                                                                        \
        if (LEAD) barrier_no_vmdrain();                                      \
        uint4 wregc[NC];                                                     \
        _Pragma("unroll")                                                    \
        for (int i = 0; i < NC; ++i)                                         \
            wregc[i] = *(const uint4*)                                       \
                (wp + wco*1024 + (KHA[i]*4 + KWA[i])*64 + wpart*8);          \
        {                                                                    \
            const int c7 = colA & 7;                                         \
            _Pragma("unroll")                                                \
            for (int j = 0; j < 8; ++j) {                                    \
                Q16 v; v.q = xreg[j];                                        \
                const int u0 = t*16 + ((j ^ c7) << 1);                       \
                Xs[u0] = v.u[0]; Xs[u0+1] = v.u[1];                          \
            }                                                                \
        }                                                                    \
        if ((t & 15) == 0) {                                                 \
            const int u2 = 256 + (t >> 4);                                   \
            const int col2 = u2 - 238;        /* row 7, cols 18..33 */       \
            const int iy = R0 + (DH) + 7, ix = col2 - 1;                     \
            const int c7 = col2 & 7;                                         \
            const bool ok = (unsigned)iy < 32u && (unsigned)ix < 32u;        \
            if (ok) {                                                        \
                const uint4* s = (const uint4*)                              \
                    (xin + ((size_t)(img*32 + iy)*32 + ix)*64);              \
                _Pragma("unroll")                                            \
                for (int j = 0; j < 8; ++j) {                                \
                    Q16 v; v.q = s[j];                                       \
                    const int u0 = u2*16 + ((j ^ c7) << 1);                  \
                    Xs[u0] = v.u[0]; Xs[u0+1] = v.u[1];                      \
                }                                                            \
            } else {                                                         \
                _Pragma("unroll")                                            \
                for (int j = 0; j < 8; ++j) {                                \
                    const int u0 = u2*16 + ((j ^ c7) << 1);                  \
                    Xs[u0] = 0ull; Xs[u0+1] = 0ull;                          \
                }                                                            \
            }                                                                \
        }                                                                    \
        _Pragma("unroll")                                                    \
        for (int i = 0; i < NC; ++i) {                                       \
            Q16 v; v.q = wregc[i];                                           \
            const int u0 = wco*16 + ((wpart ^ (wco & 7)) << 1);              \
            Wls[i][u0] = v.u[0]; Wls[i][u0+1] = v.u[1];                      \
        }                                                                    \
        if (HASNEXT) issueX(NEXTDH);                                         \
        asm volatile("s_waitcnt lgkmcnt(0)" ::: "memory");                   \
        __builtin_amdgcn_sched_barrier(0);                                   \
        __builtin_amdgcn_s_barrier();                                        \
        __builtin_amdgcn_sched_barrier(0);                                   \
        _Pragma("unroll")                                                    \
        for (int i = 0; i < NC; ++i) {                                       \
            const int dwv = DWA[i], p = PA[i];                               \
            const int colx = l31 + dwv + 1;                                  \
            const int cx7  = colx & 7;                                       \
            _Pragma("unroll")                                                \
            for (int kk = 0; kk < 4; ++kk) {                                 \
                const int sw = ((kk*2 + half) ^ (l31 & 7)) << 1;             \
                const int sx = ((kk*2 + half) ^ cx7) << 1;                   \
                U64x2 uw; const int rwi = l31*16 + sw;                       \
                uw.u[0] = Wls[i][rwi]; uw.u[1] = Wls[i][rwi+1];              \
                _Pragma("unroll")                                            \
                for (int b = 0; b < 2; ++b) {                                \
                    const int unit = (wave*2 + b)*34 + colx;                 \
                    U64x2 ux; const int rx = unit*16 + sx;                   \
                    ux.u[0] = Xs[rx]; ux.u[1] = Xs[rx+1];                    \
                    acc[p][b] = __builtin_amdgcn_mfma_f32_32x32x16_f16(      \
                        uw.v, ux.v, acc[p][b], 0, 0, 0);                     \
                }                                                            \
            }                                                                \
        }                                                                    \
    }

__global__ __launch_bounds__(256,2) void deconv4_mfma(
    const f16* __restrict__ xin, const f16* __restrict__ wp,
    float* __restrict__ out)
{
    __shared__ unsigned long long Xs[272*16];     // 34,816 B halo band
    __shared__ unsigned long long Wls[8][32*16];  // 32,768 B

    const int t   = threadIdx.x;
    const int bx  = blockIdx.x;

    const int img = (bx*256) >> 10;
    const int R0  = ((bx*256) & 1023) >> 5;       // first of 8 band rows

    const int wco   = t >> 3;
    const int wpart = t & 7;

    const int wave = t >> 6, lane = t & 63, half = lane >> 5, l31 = lane & 31;
    const int sp_w = wave * 64;

    const int rowA = t / 34, colA = t % 34;       // main staging unit = t

    f32x16 acc[4][2];
    #pragma unroll
    for (int p = 0; p < 4; ++p)
        #pragma unroll
        for (int b = 0; b < 2; ++b)
            #pragma unroll
            for (int r = 0; r < 16; ++r) acc[p][b][r] = 0.f;

    uint4 xreg[8];

    auto issueX = [&](int dh) {
        const int iy = R0 + dh + rowA, ix = colA - 1;
        const bool ok = (unsigned)iy < 32u && (unsigned)ix < 32u;
        if (ok) {
            const uint4* s = (const uint4*)
                (xin + ((size_t)(img*32 + iy)*32 + ix)*64);
            #pragma unroll
            for (int j = 0; j < 8; ++j) xreg[j] = s[j];
        } else {
            #pragma unroll
            for (int j = 0; j < 8; ++j) xreg[j] = uint4{0u,0u,0u,0u};
        }
    };

    issueX(-1);

    D4_PHASE(-1, D4P0, D4KH0, D4KW0, D4DW0, 4, false, true, 0)
    D4_PHASE( 0, D4P1, D4KH1, D4KW1, D4DW1, 8, true,  true, 1)
    D4_PHASE( 1, D4P2, D4KH2, D4KW2, D4DW2, 4, true,  false, 0)

    if (half == 0) {
        #pragma unroll
        for (int p = 0; p < 4; ++p) {
            const int poh = p >> 1, pw = p & 1;
            #pragma unroll
            for (int b = 0; b < 2; ++b) {
                const int gsp = bx*256 + sp_w + b*32 + l31;
                const int im  = gsp >> 10;
                const int r   = gsp & 1023;
                const int oh  = 2*(r >> 5) + poh;
                const int ow  = 2*(r & 31) + pw;
                #pragma unroll
                for (int co = 0; co < 3; ++co)
                    out[(((size_t)im*3 + co)*64 + oh)*64 + ow] =
                        fast_tanh(acc[p][b][co]);
            }
        }
    }
}

// ---------------------------------------------------------------------------
// prep kernels (verified)
// ---------------------------------------------------------------------------
__global__ __launch_bounds__(256) void prep_x(
    const float* __restrict__ x, f16* __restrict__ xp)
{
    const int i = blockIdx.x*256 + threadIdx.x;
    const int n = i >> 12, p = i & 4095;
    const float* b = x + (size_t)n*12288 + p;
    union { _Float16 h[4]; unsigned long long u; } o;
    o.h[0] = (_Float16)b[0];
    o.h[1] = (_Float16)b[4096];
    o.h[2] = (_Float16)b[8192];
    o.h[3] = (_Float16)0.f;
    *(unsigned long long*)(xp + (size_t)i*4) = o.u;
}

__global__ __launch_bounds__(256) void prep_w1(
    const float* __restrict__ w1, f16* __restrict__ wp)
{
    const int e = blockIdx.x*256 + threadIdx.x;
    const int co = e >> 6, k = e & 63, tap = k >> 2, ci = k & 3;
    const float v = (ci < 3) ? w1[(co*3 + ci)*16 + tap] : 0.f;
    wp[e] = (_Float16)v;
}

__global__ __launch_bounds__(256) void prep_w4(
    const float* __restrict__ dw4, f16* __restrict__ wp)
{
    const int e = blockIdx.x*256 + threadIdx.x;
    const int co = e >> 10, r = e & 1023, khw = r >> 6, ci = r & 63;
    const float v = (co < 3) ? dw4[(ci*3 + co)*16 + khw] : 0.f;
    wp[e] = (_Float16)v;
}

__global__ __launch_bounds__(256) void prep_w(
    const float* __restrict__ w2, const float* __restrict__ w3,
    const float* __restrict__ w4, const float* __restrict__ dw1,
    const float* __restrict__ dw2, const float* __restrict__ dw3,
    f16* __restrict__ dst)
{
    const int e = blockIdx.x*256 + threadIdx.x;
    float v;
    if (e < 131072) {
        int co = e >> 10, r = e & 1023, khw = r >> 6, ci = r & 63;
        v = w2[(co*64 + ci)*16 + khw];
    } else if (e < 655360) {
        int l = e - 131072;
        int co = l >> 11, r = l & 2047, khw = r >> 7, ci = r & 127;
        v = w3[(co*128 + ci)*16 + khw];
    } else if (e < 2752512) {
        int l = e - 655360;
        int co = l >> 12, r = l & 4095, khw = r >> 8, ci = r & 255;
        v = w4[(co*256 + ci)*16 + khw];
    } else if (e < 4849664) {
        int l = e - 2752512;
        int co = l >> 13, r = l & 8191, khw = r >> 9, ci = r & 511;
        v = dw1[(ci*256 + co)*16 + khw];
    } else if (e < 5373952) {
        int l = e - 4849664;
        int co = l >> 12, r = l & 4095, khw = r >> 8, ci = r & 255;
        v = dw2[(ci*128 + co)*16 + khw];
    } else {
        int l = e - 5373952;
        int co = l >> 11, r = l & 2047, khw = r >> 7, ci = r & 127;
        v = dw3[(ci*64 + co)*16 + khw];
    }
    dst[e] = (_Float16)v;
}

// ---------------------------------------------------------------------------
// BN kernels
// ---------------------------------------------------------------------------
template<typename T, int P>
__global__ __launch_bounds__(256) void bn_partial(
    const T* __restrict__ x, size_t ps, float* __restrict__ psum,
    float* __restrict__ psq, int C, int rowsPerS, int S)
{
    const int s = blockIdx.x;
    const int c = (blockIdx.y << 6) + (threadIdx.x & 63);
    float a = 0.f, q = 0.f;
    const int rEnd = (s + 1) * rowsPerS;
    for (int r = s*rowsPerS + (threadIdx.x >> 6); r < rEnd; r += 4) {
        float v = 0.f;
        #pragma unroll
        for (int p = 0; p < P; ++p)
            v += (float)x[p*ps + (size_t)r * C + c];
        a += v; q += v * v;
    }
    __shared__ float ls[256], lq[256];
    ls[threadIdx.x] = a; lq[threadIdx.x] = q;
    __syncthreads();
    if (threadIdx.x < 64) {
        a = ls[threadIdx.x] + ls[threadIdx.x+64] + ls[threadIdx.x+128] + ls[threadIdx.x+192];
        q = lq[threadIdx.x] + lq[threadIdx.x+64] + lq[threadIdx.x+128] + lq[threadIdx.x+192];
        psum[c * S + s] = a; psq[c * S + s] = q;
    }
}

__global__ __launch_bounds__(256) void bn_finalize(
    const float* __restrict__ psum, const float* __restrict__ psq,
    const float* __restrict__ gamma, const float* __restrict__ beta,
    float* __restrict__ scale, float* __restrict__ shift,
    int C, int S, float inv_count)
{
    int c = blockIdx.x * 256 + threadIdx.x;
    if (c >= C) return;
    float s = 0.f, q = 0.f;
    for (int i = 0; i < S; ++i) { s += psum[c*S + i]; q += psq[c*S + i]; }
    float m   = s * inv_count;
    float var = q * inv_count - m * m;
    var = var < 0.f ? 0.f : var;
    float sc = gamma[c] * rsqrtf(var + 1e-5f);
    scale[c] = sc;
    shift[c] = beta[c] - m * sc;
}

// affine+act with finalize fused; grid-stride with hoisted scale/shift.
__global__ __launch_bounds__(256) void bn_act16f(
    f16* __restrict__ x, const float* __restrict__ psum, const float* __restrict__ psq,
    const float* __restrict__ gamma, const float* __restrict__ beta,
    int Cmask, float inv_count, float slope, size_t n8)
{
    const size_t base = (size_t)blockIdx.x*256 + threadIdx.x;
    const int c0 = (int)((base * 8) & (size_t)Cmask);
    float sc[8], sh[8];
    #pragma unroll
    for (int j = 0; j < 8; ++j) {
        const int c = c0 + j;
        float m   = psum[c] * inv_count;
        float var = psq[c] * inv_count - m * m;
        var = var < 0.f ? 0.f : var;
        float s = gamma[c] * rsqrtf(var + 1e-5f);
        sc[j] = s;
        sh[j] = beta[c] - m * s;
    }
    const size_t stride = (size_t)gridDim.x * 256;
    for (size_t i = base; i < n8; i += stride) {
        union { uint4 u; _Float16 h[8]; } a;
        a.u = *(const uint4*)(x + i*8);
        #pragma unroll
        for (int j = 0; j < 8; ++j) {
            float v = (float)a.h[j] * sc[j] + sh[j];
            a.h[j] = (_Float16)(v >= 0.f ? v : slope * v);
        }
        *(uint4*)(x + i*8) = a.u;
    }
}

template<int P>
__global__ __launch_bounds__(256) void bn_act32(
    const float* __restrict__ x, size_t ps, f16* __restrict__ y,
    const float* __restrict__ sc, const float* __restrict__ sh,
    int Cmask, float slope)
{
    const size_t i8 = ((size_t)blockIdx.x*256 + threadIdx.x) * 8;
    float xv[8] = {0,0,0,0,0,0,0,0};
    #pragma unroll
    for (int p = 0; p < P; ++p) {
        float4 v0 = *(const float4*)(x + p*ps + i8);
        float4 v1 = *(const float4*)(x + p*ps + i8 + 4);
        xv[0]+=v0.x; xv[1]+=v0.y; xv[2]+=v0.z; xv[3]+=v0.w;
        xv[4]+=v1.x; xv[5]+=v1.y; xv[6]+=v1.z; xv[7]+=v1.w;
    }
    union { uint4 u; _Float16 h[8]; } a;
    const int c0 = (int)(i8 & (size_t)Cmask);
    #pragma unroll
    for (int j = 0; j < 8; ++j) {
        float v = xv[j] * sc[c0+j] + sh[c0+j];
        a.h[j] = (_Float16)(v >= 0.f ? v : slope * v);
    }
    *(uint4*)(y + i8) = a.u;
}

__global__ __launch_bounds__(256) void chanlin16(
    const f16* __restrict__ in, const float* __restrict__ w,
    const float* __restrict__ bias, f16* __restrict__ out)
{
    const int i = blockIdx.x*256 + threadIdx.x;
    const int c  = i & 511;
    const int bt = i >> 9;
    const int b  = bt >> 4, tt = bt & 15;
    const f16* src = in + ((size_t)b*16)*512 + c;
    const float* wr = w + ((size_t)c*16 + tt)*16;
    float acc = bias[c*16 + tt];
    #pragma unroll
    for (int s = 0; s < 16; ++s)
        acc = fmaf((float)src[s*512], wr[s], acc);
    out[i] = (_Float16)acc;
}

extern "C" void kernel_launch(void* const* d_in, const int* in_sizes, int n_in,
                              void* d_out, int out_size, void* d_ws, size_t ws_size,
                              hipStream_t stream)
{
    const float* x   = (const float*)d_in[0];
    const float* w1  = (const float*)d_in[1];
    const float* w2  = (const float*)d_in[2];
    const float* w3  = (const float*)d_in[3];
    const float* w4  = (const float*)d_in[4];
    const float* g1  = (const float*)d_in[5];
    const float* b1  = (const float*)d_in[6];
    const float* g2  = (const float*)d_in[7];
    const float* b2  = (const float*)d_in[8];
    const float* g3  = (const float*)d_in[9];
    const float* b3  = (const float*)d_in[10];
    const float* g4  = (const float*)d_in[11];
    const float* b4  = (const float*)d_in[12];
    const float* cww = (const float*)d_in[13];
    const float* cwb = (const float*)d_in[14];
    const float* dw1 = (const float*)d_in[15];
    const float* dw2 = (const float*)d_in[16];
    const float* dw3 = (const float*)d_in[17];
    const float* dw4 = (const float*)d_in[18];
    const float* dg1 = (const float*)d_in[19];
    const float* db1 = (const float*)d_in[20];
    const float* dg2 = (const float*)d_in[21];
    const float* db2 = (const float*)d_in[22];
    const float* dg3 = (const float*)d_in[23];
    const float* db3 = (const float*)d_in[24];

    char* WS = (char*)d_ws;
    float* psum  = (float*)WS;
    float* psq   = (float*)(WS + 65536);
    float* scale = (float*)(WS + 131072);
    float* shift = (float*)(WS + 133120);
    float* fst   = (float*)(WS + 196608);
    f16* slotA   = (f16*)(WS + 262144);
    f16* slotB   = (f16*)(WS + 262144 + 33554432);
    f16* wprep   = (f16*)(WS + 84148224);
    f16* wprep1  = wprep + 5505024;
    f16* wprep4  = wprep1 + 4096;

    f16*   A_hi  = slotA + 8388608;
    float* pB    = (float*)slotB;
    f16*   xpack = slotA;

    float* fs0 = fst;          float* fs1 = fst + 1024;
    float* fs2 = fst + 2048;   float* fs4 = fst + 4096;
    float* fs5 = fst + 5120;   float* fs6 = fst + 6144;

    hipMemsetAsync(fst, 0, 28672, stream);
    prep_w<<<21504, 256, 0, stream>>>(w2, w3, w4, dw1, dw2, dw3, wprep);
    prep_w1<<<16, 256, 0, stream>>>(w1, wprep1);
    prep_w4<<<128, 256, 0, stream>>>(dw4, wprep4);
    prep_x<<<4096, 256, 0, stream>>>(x, xpack);

    // ---- conv1 (MFMA + fused stats): xpack(slotA) -> slotB ----
    conv1_mfma<<<1024, 256, 0, stream>>>(xpack, wprep1, slotB, fs0, fs0 + 512);
    bn_act16f<<<2048, 256, 0, stream>>>(slotB, fs0, fs0 + 512, g1, b1, 63,
                                        1.f/262144.f, 0.2f, (size_t)2097152);

    // ---- conv2 (COB=128/CO_FR=2): slotB -> slotA ----
    mfma_conv<64,32,32,16,16,128, 128,256,1,2,false,false><<<dim3(256,1,1), 256, 0, stream>>>(
        slotB, wprep, slotA, nullptr, 0, fs1, fs1 + 512);
    bn_act16f<<<2048, 256, 0, stream>>>(slotA, fs1, fs1 + 512, g2, b2, 127,
                                        1.f/65536.f, 0.2f, (size_t)1048576);

    // ---- conv3 (COB=64): slotA -> A_hi f16 ----
    mfma_conv<128,16,16,8,8,256, 64,256,1,1,false,false><<<dim3(64,4,1), 256, 0, stream>>>(
        slotA, wprep + 131072, A_hi, nullptr, 0, fs2, fs2 + 512);
    bn_act16f<<<2048, 256, 0, stream>>>(A_hi, fs2, fs2 + 512, g3, b3, 255,
                                        1.f/16384.f, 0.2f, (size_t)524288);

    // ---- conv4 (KS=4, COB=128/CO_FR=2): A_hi -> pB ----
    mfma_conv<256,8,8,4,4,512, 128,256,4,2,false,false><<<dim3(16,4,4), 256, 0, stream>>>(
        A_hi, wprep + 655360, nullptr, pB, (size_t)2097152, nullptr, nullptr);
    bn_partial<float,4><<<dim3(32,8), 256, 0, stream>>>(pB, (size_t)2097152, psum, psq, 512, 128, 32);
    bn_finalize<<<2, 256, 0, stream>>>(psum, psq, g4, b4, scale, shift, 512, 32, 1.f/4096.f);
    bn_act32<4><<<1024, 256, 0, stream>>>(pB, (size_t)2097152, slotA, scale, shift, 511, 0.2f);

    // ---- channel-wise linear: slotA(lo) -> slotB(lo) ----
    chanlin16<<<8192, 256, 0, stream>>>(slotA, cww, cwb, slotB);

    // ---- deconv1 (COB=64): slotB(lo) -> A_hi ----
    mfma_conv<512,4,4,8,8,256, 64,256,1,1,true,false><<<dim3(16,4,4), 256, 0, stream>>>(
        slotB, wprep + 2752512, A_hi, nullptr, 0, fs4, fs4 + 512);
    bn_act16f<<<2048, 256, 0, stream>>>(A_hi, fs4, fs4 + 512, dg1, db1, 255,
                                        1.f/16384.f, 0.f, (size_t)524288);

    // ---- deconv2 (COB=128/CO_FR=2): A_hi -> slotB(lo) ----
    mfma_conv<256,8,8,16,16,128, 128,256,1,2,true,false><<<dim3(64,1,4), 256, 0, stream>>>(
        A_hi, wprep + 4849664, slotB, nullptr, 0, fs5, fs5 + 512);
    bn_act16f<<<2048, 256, 0, stream>>>(slotB, fs5, fs5 + 512, dg2, db2, 127,
                                        1.f/65536.f, 0.f, (size_t)1048576);

    // ---- deconv3 (HALO pw-fold): slotB(lo) -> slotA ----
    deconv3_pwf<<<dim3(256,2), 256, 0, stream>>>(
        slotB, wprep + 5373952, slotA, fs6, fs6 + 512);
    bn_act16f<<<2048, 256, 0, stream>>>(slotA, fs6, fs6 + 512, dg3, db3, 63,
                                        1.f/262144.f, 0.f, (size_t)2097152);

    // ---- deconv4 (MFMA, halo-staged) + tanh: slotA -> d_out ----
    deconv4_mfma<<<1024, 256, 0, stream>>>(slotA, wprep4, (float*)d_out);
}

// Round 17
// 519.944 us; speedup vs baseline: 1.0288x; 1.0288x over previous
//
#include <hip/hip_runtime.h>
#include <math.h>

typedef _Float16 f16;
typedef __attribute__((ext_vector_type(8))) _Float16 f16x8;
typedef __attribute__((ext_vector_type(16))) float f32x16;

union U64x2 { unsigned long long u[2]; f16x8 v; };
union Q16   { uint4 q; unsigned long long u[2]; };

constexpr int ilog2c(int x) { return x <= 1 ? 0 : 1 + ilog2c(x >> 1); }

__device__ __forceinline__ float fast_tanh(float x) {
    float e = __expf(2.f * x);
    return (e - 1.f) / (e + 1.f);
}

// Fenced raw barrier: LDS-safe, does NOT drain vmcnt.
__device__ __forceinline__ void barrier_no_vmdrain() {
    asm volatile("s_waitcnt lgkmcnt(0)" ::: "memory");
    __builtin_amdgcn_sched_barrier(0);
    __builtin_amdgcn_s_barrier();
    __builtin_amdgcn_sched_barrier(0);
}

// ===========================================================================
// fp16 MFMA implicit-GEMM conv/deconv (k4 s2 p1), NHWC activations.
// Round-27 = round-15 exact reproduction (verified best, 521.9us).
// Round-16's deconv3 halo variant spilled (FETCH/WRITE doubled at 128 VGPR);
// deconv3_pwf reverted to the round-24 version (verified 45us, no spill).
// ===========================================================================
template<int CIN,int IH,int IW,int OH,int OW,int COUT,int COB,int SPT,int KS,
         int CO_FR,bool DEC,bool PAIR>
__global__ __launch_bounds__(256,2) void mfma_conv(
    const f16* __restrict__ xin, const f16* __restrict__ wp,
    f16* __restrict__ out16, float* __restrict__ out32, size_t ps,
    float* __restrict__ psumF, float* __restrict__ psqF)
{
    constexpr int OHo  = DEC ? OH/2 : OH;
    constexpr int OWo  = DEC ? OW/2 : OW;
    constexpr int KTOT = CIN * (DEC ? 4 : 16);
    constexpr int CH   = (KTOT/64) / KS;
    constexpr int RPT  = CIN / 64;
    constexpr int RSH  = (RPT==1?0:RPT==2?1:RPT==4?2:3);
    constexpr int WSTR = CIN * 16;
    constexpr int TPR  = 256 / COB;
    constexpr int SPB  = OHo * OWo;
    constexpr int LSPB = ilog2c(SPB);
    constexpr int LOWo = ilog2c(OWo);

    static_assert(!PAIR || (RPT >= 2 && CH % 2 == 0), "PAIR needs RPT>=2");
    constexpr int CHU  = PAIR ? CH/2 : CH;      // outer chunk count
    constexpr int RW   = PAIR ? 32 : 16;        // ull per LDS row
    constexpr int PM   = PAIR ? 15 : 7;         // pair-swizzle mask
    constexpr int KKN  = PAIR ? 8 : 4;          // kk steps per chunk
    constexpr int XU4  = PAIR ? 16 : 8;         // uint4/thread X
    constexpr int WSEG = (PAIR ? 128 : 64)/TPR; // f16/thread W
    constexpr int WU4  = WSEG / 8;              // uint4/thread W

    __shared__ unsigned long long Xs[SPT*RW];
    __shared__ unsigned long long Wls[COB*RW];

    const int t   = threadIdx.x;
    const int bx  = blockIdx.x;
    const int cob = blockIdx.y;
    const int bz  = blockIdx.z;
    const int par = DEC ? (bz & 3) : 0;
    const int ks  = DEC ? (bz >> 2) : bz;
    const int poh = par >> 1, pw = par & 1;

    const int gsp_s = bx*SPT + t;
    const int img_s = gsp_s >> LSPB;
    const int r_s   = gsp_s & (SPB-1);
    const int oy_s  = r_s >> LOWo;
    const int ox_s  = r_s & (OWo-1);

    const int wco   = t / TPR;
    const int wpart = t % TPR;
    const f16* wbase = wp + (size_t)(cob*COB + wco)*WSTR + wpart*WSEG;

    const int wave = t >> 6, lane = t & 63, half = lane >> 5, l31 = lane & 31;
    const int co_w = (wave >> 1) * (CO_FR*32);
    const int sp_w = (wave & 1) * 128;
    const int swz  = l31 & PM;   // row&PM for every row this lane reads

    f32x16 acc[CO_FR][4];
    #pragma unroll
    for (int i = 0; i < CO_FR; ++i)
        #pragma unroll
        for (int b = 0; b < 4; ++b)
            #pragma unroll
            for (int r = 0; r < 16; ++r) acc[i][b][r] = 0.f;

    uint4 xreg[XU4];
    uint4 wreg[WU4];

    auto issue = [&](int cc) {
        const int gc  = ks*CH + (PAIR ? 2*cc : cc);
        const int tap = gc >> RSH;
        const int ci0 = (gc & (RPT-1)) << 6;    // PAIR: covers ci0..ci0+127
        int kh, kw, ih, iw;
        if (DEC) {
            const int t2h = tap >> 1, t2w = tap & 1;
            kh = (1-poh) + 2*t2h; kw = (1-pw) + 2*t2w;
            ih = oy_s + poh - t2h; iw = ox_s + pw - t2w;
        } else {
            kh = tap >> 2; kw = tap & 3;
            ih = 2*oy_s - 1 + kh; iw = 2*ox_s - 1 + kw;
        }
        const int woff = (kh*4 + kw)*CIN + ci0;
        const uint4* wsrc = (const uint4*)(wbase + woff);
        #pragma unroll
        for (int j = 0; j < WU4; ++j) wreg[j] = wsrc[j];
        const bool ok = (unsigned)ih < (unsigned)IH && (unsigned)iw < (unsigned)IW;
        if (ok) {
            const uint4* xsrc = (const uint4*)
                (xin + ((size_t)(img_s*IH + ih)*IW + iw)*CIN + ci0);
            #pragma unroll
            for (int j = 0; j < XU4; ++j) xreg[j] = xsrc[j];
        } else {
            #pragma unroll
            for (int j = 0; j < XU4; ++j) xreg[j] = uint4{0u,0u,0u,0u};
        }
    };

    issue(0);

    for (int cc = 0; cc < CHU; ++cc) {
        // LEAD barrier: raw, no vmcnt drain.
        if (cc) barrier_no_vmdrain();

        #pragma unroll
        for (int j = 0; j < WU4; ++j) {
            Q16 v; v.q = wreg[j];
            const int lp = wpart*WU4 + j;
            const int u0 = wco*RW + ((lp ^ (wco & PM)) << 1);
            Wls[u0]   = v.u[0];
            Wls[u0+1] = v.u[1];
        }
        {
            #pragma unroll
            for (int j = 0; j < XU4; ++j) {
                Q16 v; v.q = xreg[j];
                const int u0 = t*RW + ((j ^ (t & PM)) << 1);
                Xs[u0]   = v.u[0];
                Xs[u0+1] = v.u[1];
            }
        }

        // issue NEXT chunk's global loads — in flight across both barriers.
        if (cc + 1 < CHU) issue(cc + 1);

        asm volatile("s_waitcnt lgkmcnt(0)" ::: "memory"); // my ds_writes visible
        __builtin_amdgcn_sched_barrier(0);                 // nothing crosses
        __builtin_amdgcn_s_barrier();                      // NO vmcnt drain
        __builtin_amdgcn_sched_barrier(0);                 // ds_reads stay below

        #pragma unroll
        for (int kk = 0; kk < KKN; ++kk) {
            const int so = ((kk*2 + half) ^ swz) << 1;
            f16x8 wf[CO_FR], xf[4];
            #pragma unroll
            for (int i = 0; i < CO_FR; ++i) {
                U64x2 u; const int rw = (co_w + i*32 + l31)*RW + so;
                u.u[0] = Wls[rw]; u.u[1] = Wls[rw+1]; wf[i] = u.v;
            }
            #pragma unroll
            for (int b = 0; b < 4; ++b) {
                U64x2 u; const int rx = (sp_w + b*32 + l31)*RW + so;
                u.u[0] = Xs[rx]; u.u[1] = Xs[rx+1]; xf[b] = u.v;
            }
            #pragma unroll
            for (int i = 0; i < CO_FR; ++i)
                #pragma unroll
                for (int b = 0; b < 4; ++b)
                    acc[i][b] = __builtin_amdgcn_mfma_f32_32x32x16_f16(
                        xf[b], wf[i], acc[i][b], 0, 0, 0);
        }
    }

    #pragma unroll
    for (int b = 0; b < 4; ++b) {
        #pragma unroll
        for (int q = 0; q < 4; ++q) {
            #pragma unroll
            for (int r2 = 0; r2 < 4; ++r2) {
                const int sp_loc = sp_w + b*32 + q*8 + 4*half + r2;
                const int gsp    = bx*SPT + sp_loc;
                size_t base;
                if (DEC) {
                    const int img = gsp >> LSPB;
                    const int r   = gsp & (SPB-1);
                    const int oh  = 2*(r >> LOWo) + poh;
                    const int ow  = 2*(r & (OWo-1)) + pw;
                    base = ((size_t)(img*OH + oh)*OW + ow)*COUT + cob*COB;
                } else {
                    base = (size_t)gsp*COUT + cob*COB;
                }
                #pragma unroll
                for (int i = 0; i < CO_FR; ++i) {
                    const int co_l = co_w + i*32 + l31;
                    const float v  = acc[i][b][q*4 + r2];
                    if (KS == 1) out16[base + co_l] = (_Float16)v;
                    else         out32[(size_t)ks*ps + base + co_l] = v;
                }
            }
        }
    }

    if (KS == 1 && psumF != nullptr) {
        // per-wave partials
        float sArr[CO_FR], qArr[CO_FR];
        #pragma unroll
        for (int i = 0; i < CO_FR; ++i) {
            float s = 0.f, q = 0.f;
            #pragma unroll
            for (int b = 0; b < 4; ++b)
                #pragma unroll
                for (int r = 0; r < 16; ++r) {
                    const float v = acc[i][b][r];
                    s += v; q += v * v;
                }
            s += __shfl_down(s, 32);
            q += __shfl_down(q, 32);
            sArr[i] = s; qArr[i] = q;
        }
        // block-level LDS reduction: 4 wave-partials -> 1 wave-atomic/array
        __syncthreads();                       // Xs reads complete everywhere
        float* LS = (float*)Xs;                // 4*CO_FR*32 floats
        float* LQ = LS + 4*CO_FR*32;
        if (half == 0) {
            #pragma unroll
            for (int i = 0; i < CO_FR; ++i) {
                LS[(wave*CO_FR + i)*32 + l31] = sArr[i];
                LQ[(wave*CO_FR + i)*32 + l31] = qArr[i];
            }
        }
        __syncthreads();
        if (t < COB) {
            constexpr int KSH = (CO_FR == 1 ? 5 : 6);
            const int k  = t >> KSH;
            const int ii = (CO_FR == 1) ? 0 : ((t >> 5) & 1);
            const int l  = t & 31;
            const int i0 = ((2*k)  *CO_FR + ii)*32 + l;
            const int i1 = ((2*k+1)*CO_FR + ii)*32 + l;
            atomicAdd(psumF + cob*COB + t, LS[i0] + LS[i1]);
            atomicAdd(psqF  + cob*COB + t, LQ[i0] + LQ[i1]);
        }
    }
}

// ---------------------------------------------------------------------------
// conv1 via MFMA + fused BN stats (single stage). Packed+swizzled LDS
// (40,960 B); launch_bounds(256,2). Block-reduced stat atomics.
// ---------------------------------------------------------------------------
__global__ __launch_bounds__(256,2) void conv1_mfma(
    const f16* __restrict__ xp, const f16* __restrict__ wp,
    f16* __restrict__ out, float* __restrict__ psumF, float* __restrict__ psqF)
{
    __shared__ unsigned long long Xs[256*16];
    __shared__ unsigned long long Wls[64*16];
    const int t = threadIdx.x, bx = blockIdx.x;

    {
        const int r = t >> 2, part = t & 3;
        const uint4* src = (const uint4*)(wp + r*64 + part*16);
        Q16 v0; v0.q = src[0];
        Q16 v1; v1.q = src[1];
        const int a0 = r*16 + (((part*2)   ^ (r & 7)) << 1);
        const int a1 = r*16 + (((part*2+1) ^ (r & 7)) << 1);
        Wls[a0]   = v0.u[0]; Wls[a0+1] = v0.u[1];
        Wls[a1]   = v1.u[0]; Wls[a1+1] = v1.u[1];
    }
    {
        const int gsp = bx*256 + t;
        const int n = gsp >> 10, r = gsp & 1023;
        const int oy = r >> 5, ox = r & 31;
        const int ih0 = 2*oy - 1, iw0 = 2*ox - 1;
        #pragma unroll
        for (int tap = 0; tap < 16; ++tap) {
            const int ih = ih0 + (tap >> 2), iw = iw0 + (tap & 3);
            unsigned long long v = 0ull;
            if ((unsigned)ih < 64u && (unsigned)iw < 64u)
                v = *(const unsigned long long*)(xp + (((size_t)n*64 + ih)*64 + iw)*4);
            const int u = t*16 + (((tap >> 1) ^ (t & 7)) << 1) + (tap & 1);
            Xs[u] = v;
        }
    }
    __syncthreads();

    const int wave = t >> 6, lane = t & 63, half = lane >> 5, l31 = lane & 31;
    const int co_w = (wave >> 1) * 32;
    const int sp_w = (wave & 1) * 128;
    const int swz  = l31 & 7;

    f32x16 acc[4];
    #pragma unroll
    for (int b = 0; b < 4; ++b)
        #pragma unroll
        for (int r = 0; r < 16; ++r) acc[b][r] = 0.f;

    #pragma unroll
    for (int kk = 0; kk < 4; ++kk) {
        const int so = ((kk*2 + half) ^ swz) << 1;
        U64x2 uw; const int rw = (co_w + l31)*16 + so;
        uw.u[0] = Wls[rw]; uw.u[1] = Wls[rw+1];
        #pragma unroll
        for (int b = 0; b < 4; ++b) {
            U64x2 ux; const int rx = (sp_w + b*32 + l31)*16 + so;
            ux.u[0] = Xs[rx]; ux.u[1] = Xs[rx+1];
            acc[b] = __builtin_amdgcn_mfma_f32_32x32x16_f16(
                ux.v, uw.v, acc[b], 0, 0, 0);
        }
    }
    #pragma unroll
    for (int b = 0; b < 4; ++b)
        #pragma unroll
        for (int q = 0; q < 4; ++q)
            #pragma unroll
            for (int r2 = 0; r2 < 4; ++r2) {
                const int sp_loc = sp_w + b*32 + q*8 + 4*half + r2;
                out[(size_t)(bx*256 + sp_loc)*64 + co_w + l31] =
                    (_Float16)acc[b][q*4 + r2];
            }

    float s = 0.f, q = 0.f;
    #pragma unroll
    for (int b = 0; b < 4; ++b)
        #pragma unroll
        for (int r = 0; r < 16; ++r) {
            const float v = acc[b][r];
            s += v; q += v * v;
        }
    s += __shfl_down(s, 32);
    q += __shfl_down(q, 32);
    __syncthreads();                       // Xs reads complete everywhere
    {
        float* LS = (float*)Xs;            // 4*32 floats
        float* LQ = LS + 128;
        if (half == 0) {
            LS[wave*32 + l31] = s;
            LQ[wave*32 + l31] = q;
        }
        __syncthreads();
        if (t < 64) {
            const int k = t >> 5, l = t & 31;
            atomicAdd(psumF + t, LS[(2*k)*32 + l] + LS[(2*k+1)*32 + l]);
            atomicAdd(psqF  + t, LQ[(2*k)*32 + l] + LQ[(2*k+1)*32 + l]);
        }
    }
}

// ---------------------------------------------------------------------------
// deconv3 (128->64, 16x16 -> 32x32) PW-PARITY-FOLDED (round 24, verified
// 45us). Grid (256, 2): bx = spatial tile, by = poh. 12 staging units.
// LDS 49,152 B. (Round-16 halo variant spilled — reverted.)
// ---------------------------------------------------------------------------
__global__ __launch_bounds__(256,2) void deconv3_pwf(
    const f16* __restrict__ xin, const f16* __restrict__ wp,
    f16* __restrict__ out, float* __restrict__ psumF, float* __restrict__ psqF)
{
    __shared__ unsigned long long Xs[256*16];
    __shared__ unsigned long long Wls[2][64*16];

    const int t   = threadIdx.x;
    const int bx  = blockIdx.x;
    const int poh = blockIdx.y;

    const int gsp_s = bx*256 + t;
    const int img_s = gsp_s >> 8;
    const int r_s   = gsp_s & 255;
    const int oy_s  = r_s >> 4;
    const int ox_s  = r_s & 15;

    const int wco   = t >> 2;       // TPR=4 (COB=64)
    const int wpart = t & 3;
    const f16* wbase = wp + (size_t)wco*2048 + wpart*16;   // WSTR=128*16

    const int wave = t >> 6, lane = t & 63, half = lane >> 5, l31 = lane & 31;
    const int co_w = (wave >> 1) * 32;
    const int sp_w = (wave & 1) * 128;
    const int swz  = l31 & 7;

    f32x16 acc[2][4];   // [pw][sp-block]
    #pragma unroll
    for (int p = 0; p < 2; ++p)
        #pragma unroll
        for (int b = 0; b < 4; ++b)
            #pragma unroll
            for (int r = 0; r < 16; ++r) acc[p][b][r] = 0.f;

    uint4 xreg[8];
    uint4 wregP[2][2];

    // unit cc -> (seg, dwi, t2h):  seg = cc&1, dwi = (cc>>1)%3, t2h = (cc>>1)/3
    auto issue = [&](int cc) {
        const int seg  = cc & 1;
        const int rest = cc >> 1;
        const int dwi  = rest % 3;
        const int t2h  = rest / 3;
        const int dh = poh - t2h, dw = dwi - 1;
        const int ih = oy_s + dh, iw = ox_s + dw;
        const int ci0 = seg << 6;
        #pragma unroll
        for (int p = 0; p < 2; ++p) {
            const int t2w = p - dw;
            if (t2w == 0 || t2w == 1) {
                const int kh = (1-poh) + 2*t2h, kw = (1-p) + 2*t2w;
                const uint4* wsrc = (const uint4*)(wbase + (kh*4 + kw)*128 + ci0);
                wregP[p][0] = wsrc[0];
                wregP[p][1] = wsrc[1];
            }
        }
        const bool ok = (unsigned)ih < 16u && (unsigned)iw < 16u;
        if (ok) {
            const uint4* xsrc = (const uint4*)
                (xin + ((size_t)(img_s*16 + ih)*16 + iw)*128 + ci0);
            #pragma unroll
            for (int j = 0; j < 8; ++j) xreg[j] = xsrc[j];
        } else {
            #pragma unroll
            for (int j = 0; j < 8; ++j) xreg[j] = uint4{0u,0u,0u,0u};
        }
    };

    issue(0);

    for (int cc = 0; cc < 12; ++cc) {
        const int rest = cc >> 1;
        const int dw   = rest % 3 - 1;

        if (cc) barrier_no_vmdrain();

        // stage W for active pw combos
        #pragma unroll
        for (int p = 0; p < 2; ++p) {
            const int t2w = p - dw;
            if (t2w == 0 || t2w == 1) {
                #pragma unroll
                for (int j = 0; j < 2; ++j) {
                    Q16 v; v.q = wregP[p][j];
                    const int lp = wpart*2 + j;
                    const int u0 = wco*16 + ((lp ^ (wco & 7)) << 1);
                    Wls[p][u0]   = v.u[0];
                    Wls[p][u0+1] = v.u[1];
                }
            }
        }
        // stage X
        #pragma unroll
        for (int j = 0; j < 8; ++j) {
            Q16 v; v.q = xreg[j];
            const int u0 = t*16 + ((j ^ (t & 7)) << 1);
            Xs[u0]   = v.u[0];
            Xs[u0+1] = v.u[1];
        }

        if (cc + 1 < 12) issue(cc + 1);

        asm volatile("s_waitcnt lgkmcnt(0)" ::: "memory");
        __builtin_amdgcn_sched_barrier(0);
        __builtin_amdgcn_s_barrier();
        __builtin_amdgcn_sched_barrier(0);

        #pragma unroll
        for (int kk = 0; kk < 4; ++kk) {
            const int so = ((kk*2 + half) ^ swz) << 1;
            f16x8 xf[4];
            #pragma unroll
            for (int b = 0; b < 4; ++b) {
                U64x2 u; const int rx = (sp_w + b*32 + l31)*16 + so;
                u.u[0] = Xs[rx]; u.u[1] = Xs[rx+1]; xf[b] = u.v;
            }
            #pragma unroll
            for (int p = 0; p < 2; ++p) {
                const int t2w = p - dw;
                if (t2w == 0 || t2w == 1) {
                    U64x2 uw; const int rw = (co_w + l31)*16 + so;
                    uw.u[0] = Wls[p][rw]; uw.u[1] = Wls[p][rw+1];
                    #pragma unroll
                    for (int b = 0; b < 4; ++b)
                        acc[p][b] = __builtin_amdgcn_mfma_f32_32x32x16_f16(
                            xf[b], uw.v, acc[p][b], 0, 0, 0);
                }
            }
        }
    }

    #pragma unroll
    for (int p = 0; p < 2; ++p) {
        #pragma unroll
        for (int b = 0; b < 4; ++b) {
            #pragma unroll
            for (int q = 0; q < 4; ++q) {
                #pragma unroll
                for (int r2 = 0; r2 < 4; ++r2) {
                    const int sp_loc = sp_w + b*32 + q*8 + 4*half + r2;
                    const int gsp    = bx*256 + sp_loc;
                    const int img    = gsp >> 8;
                    const int r      = gsp & 255;
                    const int oh     = 2*(r >> 4) + poh;
                    const int ow     = 2*(r & 15) + p;
                    const size_t base = ((size_t)(img*32 + oh)*32 + ow)*64;
                    out[base + co_w + l31] = (_Float16)acc[p][b][q*4 + r2];
                }
            }
        }
    }

    if (psumF != nullptr) {
        float s = 0.f, q = 0.f;
        #pragma unroll
        for (int p = 0; p < 2; ++p)
            #pragma unroll
            for (int b = 0; b < 4; ++b)
                #pragma unroll
                for (int r = 0; r < 16; ++r) {
                    const float v = acc[p][b][r];
                    s += v; q += v * v;
                }
        s += __shfl_down(s, 32);
        q += __shfl_down(q, 32);
        __syncthreads();                   // Xs reads complete everywhere
        float* LS = (float*)Xs;            // 4*32 floats
        float* LQ = LS + 128;
        if (half == 0) {
            LS[wave*32 + l31] = s;
            LQ[wave*32 + l31] = q;
        }
        __syncthreads();
        if (t < 64) {
            const int k = t >> 5, l = t & 31;
            atomicAdd(psumF + t, LS[(2*k)*32 + l] + LS[(2*k+1)*32 + l]);
            atomicAdd(psqF  + t, LQ[(2*k)*32 + l] + LQ[(2*k+1)*32 + l]);
        }
    }
}

// ---------------------------------------------------------------------------
// deconv4 (64->3) via MFMA, COUT padded to 32. HALO-staged (round 25,
// verified): 3 dh-phases, acc[4][2], grid 1024. LDS 67,584 B.
// ---------------------------------------------------------------------------
static constexpr int D4P0[4] = {0,0,1,1};
static constexpr int D4KH0[4]= {3,3,3,3};
static constexpr int D4KW0[4]= {3,1,2,0};
static constexpr int D4DW0[4]= {-1,0,0,1};
static constexpr int D4P1[8] = {0,0,1,1,2,2,3,3};
static constexpr int D4KH1[8]= {1,1,1,1,2,2,2,2};
static constexpr int D4KW1[8]= {3,1,2,0,3,1,2,0};
static constexpr int D4DW1[8]= {-1,0,0,1,-1,0,0,1};
static constexpr int D4P2[4] = {2,2,3,3};
static constexpr int D4KH2[4]= {0,0,0,0};
static constexpr int D4KW2[4]= {3,1,2,0};
static constexpr int D4DW2[4]= {-1,0,0,1};

#define D4_PHASE(DH, PA, KHA, KWA, DWA, NC, LEAD, HASNEXT, NEXTDH)           \
    {                                                                        \
        if (LEAD) barrier_no_vmdrain();                                      \
        uint4 wregc[NC];                                                     \
        _Pragma("unroll")                                                    \
        for (int i = 0; i < NC; ++i)                                         \
            wregc[i] = *(const uint4*)                                       \
                (wp + wco*1024 + (KHA[i]*4 + KWA[i])*64 + wpart*8);          \
        {                                                                    \
            const int c7 = colA & 7;                                         \
            _Pragma("unroll")                                                \
            for (int j = 0; j < 8; ++j) {                                    \
                Q16 v; v.q = xreg[j];                                        \
                const int u0 = t*16 + ((j ^ c7) << 1);                       \
                Xs[u0] = v.u[0]; Xs[u0+1] = v.u[1];                          \
            }                                                                \
        }                                                                    \
        if ((t & 15) == 0) {                                                 \
            const int u2 = 256 + (t >> 4);                                   \
            const int col2 = u2 - 238;        /* row 7, cols 18..33 */       \
            const int iy = R0 + (DH) + 7, ix = col2 - 1;                     \
            const int c7 = col2 & 7;                                         \
            const bool ok = (unsigned)iy < 32u && (unsigned)ix < 32u;        \
            if (ok) {                                                        \
                const uint4* s = (const uint4*)                              \
                    (xin + ((size_t)(img*32 + iy)*32 + ix)*64);              \
                _Pragma("unroll")                                            \
                for (int j = 0; j < 8; ++j) {                                \
                    Q16 v; v.q = s[j];                                       \
                    const int u0 = u2*16 + ((j ^ c7) << 1);                  \
                    Xs[u0] = v.u[0]; Xs[u0+1] = v.u[1];                      \
                }                                                            \
            } else {                                                         \
                _Pragma("unroll")                                            \
                for (int j = 0; j < 8; ++j) {                                \
                    const int u0 = u2*16 + ((j ^ c7) << 1);                  \
                    Xs[u0] = 0ull; Xs[u0+1] = 0ull;                          \
                }                                                            \
            }                                                                \
        }                                                                    \
        _Pragma("unroll")                                                    \
        for (int i = 0; i < NC; ++i) {                                       \
            Q16 v; v.q = wregc[i];                                           \
            const int u0 = wco*16 + ((wpart ^ (wco & 7)) << 1);              \
            Wls[i][u0] = v.u[0]; Wls[i][u0+1] = v.u[1];                      \
        }                                                                    \
        if (HASNEXT) issueX(NEXTDH);                                         \
        asm volatile("s_waitcnt lgkmcnt(0)" ::: "memory");                   \
        __builtin_amdgcn_sched_barrier(0);                                   \
        __builtin_amdgcn_s_barrier();                                        \
        __builtin_amdgcn_sched_barrier(0);                                   \
        _Pragma("unroll")                                                    \
        for (int i = 0; i < NC; ++i) {                                       \
            const int dwv = DWA[i], p = PA[i];                               \
            const int colx = l31 + dwv + 1;                                  \
            const int cx7  = colx & 7;                                       \
            _Pragma("unroll")                                                \
            for (int kk = 0; kk < 4; ++kk) {                                 \
                const int sw = ((kk*2 + half) ^ (l31 & 7)) << 1;             \
                const int sx = ((kk*2 + half) ^ cx7) << 1;                   \
                U64x2 uw; const int rwi = l31*16 + sw;                       \
                uw.u[0] = Wls[i][rwi]; uw.u[1] = Wls[i][rwi+1];              \
                _Pragma("unroll")                                            \
                for (int b = 0; b < 2; ++b) {                                \
                    const int unit = (wave*2 + b)*34 + colx;                 \
                    U64x2 ux; const int rx = unit*16 + sx;                   \
                    ux.u[0] = Xs[rx]; ux.u[1] = Xs[rx+1];                    \
                    acc[p][b] = __builtin_amdgcn_mfma_f32_32x32x16_f16(      \
                        uw.v, ux.v, acc[p][b], 0, 0, 0);                     \
                }                                                            \
            }                                                                \
        }                                                                    \
    }

__global__ __launch_bounds__(256,2) void deconv4_mfma(
    const f16* __restrict__ xin, const f16* __restrict__ wp,
    float* __restrict__ out)
{
    __shared__ unsigned long long Xs[272*16];     // 34,816 B halo band
    __shared__ unsigned long long Wls[8][32*16];  // 32,768 B

    const int t   = threadIdx.x;
    const int bx  = blockIdx.x;

    const int img = (bx*256) >> 10;
    const int R0  = ((bx*256) & 1023) >> 5;       // first of 8 band rows

    const int wco   = t >> 3;
    const int wpart = t & 7;

    const int wave = t >> 6, lane = t & 63, half = lane >> 5, l31 = lane & 31;
    const int sp_w = wave * 64;

    const int rowA = t / 34, colA = t % 34;       // main staging unit = t

    f32x16 acc[4][2];
    #pragma unroll
    for (int p = 0; p < 4; ++p)
        #pragma unroll
        for (int b = 0; b < 2; ++b)
            #pragma unroll
            for (int r = 0; r < 16; ++r) acc[p][b][r] = 0.f;

    uint4 xreg[8];

    auto issueX = [&](int dh) {
        const int iy = R0 + dh + rowA, ix = colA - 1;
        const bool ok = (unsigned)iy < 32u && (unsigned)ix < 32u;
        if (ok) {
            const uint4* s = (const uint4*)
                (xin + ((size_t)(img*32 + iy)*32 + ix)*64);
            #pragma unroll
            for (int j = 0; j < 8; ++j) xreg[j] = s[j];
        } else {
            #pragma unroll
            for (int j = 0; j < 8; ++j) xreg[j] = uint4{0u,0u,0u,0u};
        }
    };

    issueX(-1);

    D4_PHASE(-1, D4P0, D4KH0, D4KW0, D4DW0, 4, false, true, 0)
    D4_PHASE( 0, D4P1, D4KH1, D4KW1, D4DW1, 8, true,  true, 1)
    D4_PHASE( 1, D4P2, D4KH2, D4KW2, D4DW2, 4, true,  false, 0)

    if (half == 0) {
        #pragma unroll
        for (int p = 0; p < 4; ++p) {
            const int poh = p >> 1, pw = p & 1;
            #pragma unroll
            for (int b = 0; b < 2; ++b) {
                const int gsp = bx*256 + sp_w + b*32 + l31;
                const int im  = gsp >> 10;
                const int r   = gsp & 1023;
                const int oh  = 2*(r >> 5) + poh;
                const int ow  = 2*(r & 31) + pw;
                #pragma unroll
                for (int co = 0; co < 3; ++co)
                    out[(((size_t)im*3 + co)*64 + oh)*64 + ow] =
                        fast_tanh(acc[p][b][co]);
            }
        }
    }
}

// ---------------------------------------------------------------------------
// prep kernels (verified)
// ---------------------------------------------------------------------------
__global__ __launch_bounds__(256) void prep_x(
    const float* __restrict__ x, f16* __restrict__ xp)
{
    const int i = blockIdx.x*256 + threadIdx.x;
    const int n = i >> 12, p = i & 4095;
    const float* b = x + (size_t)n*12288 + p;
    union { _Float16 h[4]; unsigned long long u; } o;
    o.h[0] = (_Float16)b[0];
    o.h[1] = (_Float16)b[4096];
    o.h[2] = (_Float16)b[8192];
    o.h[3] = (_Float16)0.f;
    *(unsigned long long*)(xp + (size_t)i*4) = o.u;
}

__global__ __launch_bounds__(256) void prep_w1(
    const float* __restrict__ w1, f16* __restrict__ wp)
{
    const int e = blockIdx.x*256 + threadIdx.x;
    const int co = e >> 6, k = e & 63, tap = k >> 2, ci = k & 3;
    const float v = (ci < 3) ? w1[(co*3 + ci)*16 + tap] : 0.f;
    wp[e] = (_Float16)v;
}

__global__ __launch_bounds__(256) void prep_w4(
    const float* __restrict__ dw4, f16* __restrict__ wp)
{
    const int e = blockIdx.x*256 + threadIdx.x;
    const int co = e >> 10, r = e & 1023, khw = r >> 6, ci = r & 63;
    const float v = (co < 3) ? dw4[(ci*3 + co)*16 + khw] : 0.f;
    wp[e] = (_Float16)v;
}

__global__ __launch_bounds__(256) void prep_w(
    const float* __restrict__ w2, const float* __restrict__ w3,
    const float* __restrict__ w4, const float* __restrict__ dw1,
    const float* __restrict__ dw2, const float* __restrict__ dw3,
    f16* __restrict__ dst)
{
    const int e = blockIdx.x*256 + threadIdx.x;
    float v;
    if (e < 131072) {
        int co = e >> 10, r = e & 1023, khw = r >> 6, ci = r & 63;
        v = w2[(co*64 + ci)*16 + khw];
    } else if (e < 655360) {
        int l = e - 131072;
        int co = l >> 11, r = l & 2047, khw = r >> 7, ci = r & 127;
        v = w3[(co*128 + ci)*16 + khw];
    } else if (e < 2752512) {
        int l = e - 655360;
        int co = l >> 12, r = l & 4095, khw = r >> 8, ci = r & 255;
        v = w4[(co*256 + ci)*16 + khw];
    } else if (e < 4849664) {
        int l = e - 2752512;
        int co = l >> 13, r = l & 8191, khw = r >> 9, ci = r & 511;
        v = dw1[(ci*256 + co)*16 + khw];
    } else if (e < 5373952) {
        int l = e - 4849664;
        int co = l >> 12, r = l & 4095, khw = r >> 8, ci = r & 255;
        v = dw2[(ci*128 + co)*16 + khw];
    } else {
        int l = e - 5373952;
        int co = l >> 11, r = l & 2047, khw = r >> 7, ci = r & 127;
        v = dw3[(ci*64 + co)*16 + khw];
    }
    dst[e] = (_Float16)v;
}

// ---------------------------------------------------------------------------
// BN kernels
// ---------------------------------------------------------------------------
template<typename T, int P>
__global__ __launch_bounds__(256) void bn_partial(
    const T* __restrict__ x, size_t ps, float* __restrict__ psum,
    float* __restrict__ psq, int C, int rowsPerS, int S)
{
    const int s = blockIdx.x;
    const int c = (blockIdx.y << 6) + (threadIdx.x & 63);
    float a = 0.f, q = 0.f;
    const int rEnd = (s + 1) * rowsPerS;
    for (int r = s*rowsPerS + (threadIdx.x >> 6); r < rEnd; r += 4) {
        float v = 0.f;
        #pragma unroll
        for (int p = 0; p < P; ++p)
            v += (float)x[p*ps + (size_t)r * C + c];
        a += v; q += v * v;
    }
    __shared__ float ls[256], lq[256];
    ls[threadIdx.x] = a; lq[threadIdx.x] = q;
    __syncthreads();
    if (threadIdx.x < 64) {
        a = ls[threadIdx.x] + ls[threadIdx.x+64] + ls[threadIdx.x+128] + ls[threadIdx.x+192];
        q = lq[threadIdx.x] + lq[threadIdx.x+64] + lq[threadIdx.x+128] + lq[threadIdx.x+192];
        psum[c * S + s] = a; psq[c * S + s] = q;
    }
}

__global__ __launch_bounds__(256) void bn_finalize(
    const float* __restrict__ psum, const float* __restrict__ psq,
    const float* __restrict__ gamma, const float* __restrict__ beta,
    float* __restrict__ scale, float* __restrict__ shift,
    int C, int S, float inv_count)
{
    int c = blockIdx.x * 256 + threadIdx.x;
    if (c >= C) return;
    float s = 0.f, q = 0.f;
    for (int i = 0; i < S; ++i) { s += psum[c*S + i]; q += psq[c*S + i]; }
    float m   = s * inv_count;
    float var = q * inv_count - m * m;
    var = var < 0.f ? 0.f : var;
    float sc = gamma[c] * rsqrtf(var + 1e-5f);
    scale[c] = sc;
    shift[c] = beta[c] - m * sc;
}

// affine+act with finalize fused; grid-stride with hoisted scale/shift.
__global__ __launch_bounds__(256) void bn_act16f(
    f16* __restrict__ x, const float* __restrict__ psum, const float* __restrict__ psq,
    const float* __restrict__ gamma, const float* __restrict__ beta,
    int Cmask, float inv_count, float slope, size_t n8)
{
    const size_t base = (size_t)blockIdx.x*256 + threadIdx.x;
    const int c0 = (int)((base * 8) & (size_t)Cmask);
    float sc[8], sh[8];
    #pragma unroll
    for (int j = 0; j < 8; ++j) {
        const int c = c0 + j;
        float m   = psum[c] * inv_count;
        float var = psq[c] * inv_count - m * m;
        var = var < 0.f ? 0.f : var;
        float s = gamma[c] * rsqrtf(var + 1e-5f);
        sc[j] = s;
        sh[j] = beta[c] - m * s;
    }
    const size_t stride = (size_t)gridDim.x * 256;
    for (size_t i = base; i < n8; i += stride) {
        union { uint4 u; _Float16 h[8]; } a;
        a.u = *(const uint4*)(x + i*8);
        #pragma unroll
        for (int j = 0; j < 8; ++j) {
            float v = (float)a.h[j] * sc[j] + sh[j];
            a.h[j] = (_Float16)(v >= 0.f ? v : slope * v);
        }
        *(uint4*)(x + i*8) = a.u;
    }
}

template<int P>
__global__ __launch_bounds__(256) void bn_act32(
    const float* __restrict__ x, size_t ps, f16* __restrict__ y,
    const float* __restrict__ sc, const float* __restrict__ sh,
    int Cmask, float slope)
{
    const size_t i8 = ((size_t)blockIdx.x*256 + threadIdx.x) * 8;
    float xv[8] = {0,0,0,0,0,0,0,0};
    #pragma unroll
    for (int p = 0; p < P; ++p) {
        float4 v0 = *(const float4*)(x + p*ps + i8);
        float4 v1 = *(const float4*)(x + p*ps + i8 + 4);
        xv[0]+=v0.x; xv[1]+=v0.y; xv[2]+=v0.z; xv[3]+=v0.w;
        xv[4]+=v1.x; xv[5]+=v1.y; xv[6]+=v1.z; xv[7]+=v1.w;
    }
    union { uint4 u; _Float16 h[8]; } a;
    const int c0 = (int)(i8 & (size_t)Cmask);
    #pragma unroll
    for (int j = 0; j < 8; ++j) {
        float v = xv[j] * sc[c0+j] + sh[c0+j];
        a.h[j] = (_Float16)(v >= 0.f ? v : slope * v);
    }
    *(uint4*)(y + i8) = a.u;
}

__global__ __launch_bounds__(256) void chanlin16(
    const f16* __restrict__ in, const float* __restrict__ w,
    const float* __restrict__ bias, f16* __restrict__ out)
{
    const int i = blockIdx.x*256 + threadIdx.x;
    const int c  = i & 511;
    const int bt = i >> 9;
    const int b  = bt >> 4, tt = bt & 15;
    const f16* src = in + ((size_t)b*16)*512 + c;
    const float* wr = w + ((size_t)c*16 + tt)*16;
    float acc = bias[c*16 + tt];
    #pragma unroll
    for (int s = 0; s < 16; ++s)
        acc = fmaf((float)src[s*512], wr[s], acc);
    out[i] = (_Float16)acc;
}

extern "C" void kernel_launch(void* const* d_in, const int* in_sizes, int n_in,
                              void* d_out, int out_size, void* d_ws, size_t ws_size,
                              hipStream_t stream)
{
    const float* x   = (const float*)d_in[0];
    const float* w1  = (const float*)d_in[1];
    const float* w2  = (const float*)d_in[2];
    const float* w3  = (const float*)d_in[3];
    const float* w4  = (const float*)d_in[4];
    const float* g1  = (const float*)d_in[5];
    const float* b1  = (const float*)d_in[6];
    const float* g2  = (const float*)d_in[7];
    const float* b2  = (const float*)d_in[8];
    const float* g3  = (const float*)d_in[9];
    const float* b3  = (const float*)d_in[10];
    const float* g4  = (const float*)d_in[11];
    const float* b4  = (const float*)d_in[12];
    const float* cww = (const float*)d_in[13];
    const float* cwb = (const float*)d_in[14];
    const float* dw1 = (const float*)d_in[15];
    const float* dw2 = (const float*)d_in[16];
    const float* dw3 = (const float*)d_in[17];
    const float* dw4 = (const float*)d_in[18];
    const float* dg1 = (const float*)d_in[19];
    const float* db1 = (const float*)d_in[20];
    const float* dg2 = (const float*)d_in[21];
    const float* db2 = (const float*)d_in[22];
    const float* dg3 = (const float*)d_in[23];
    const float* db3 = (const float*)d_in[24];

    char* WS = (char*)d_ws;
    float* psum  = (float*)WS;
    float* psq   = (float*)(WS + 65536);
    float* scale = (float*)(WS + 131072);
    float* shift = (float*)(WS + 133120);
    float* fst   = (float*)(WS + 196608);
    f16* slotA   = (f16*)(WS + 262144);
    f16* slotB   = (f16*)(WS + 262144 + 33554432);
    f16* wprep   = (f16*)(WS + 84148224);
    f16* wprep1  = wprep + 5505024;
    f16* wprep4  = wprep1 + 4096;

    f16*   A_hi  = slotA + 8388608;
    float* pB    = (float*)slotB;
    f16*   xpack = slotA;

    float* fs0 = fst;          float* fs1 = fst + 1024;
    float* fs2 = fst + 2048;   float* fs4 = fst + 4096;
    float* fs5 = fst + 5120;   float* fs6 = fst + 6144;

    hipMemsetAsync(fst, 0, 28672, stream);
    prep_w<<<21504, 256, 0, stream>>>(w2, w3, w4, dw1, dw2, dw3, wprep);
    prep_w1<<<16, 256, 0, stream>>>(w1, wprep1);
    prep_w4<<<128, 256, 0, stream>>>(dw4, wprep4);
    prep_x<<<4096, 256, 0, stream>>>(x, xpack);

    // ---- conv1 (MFMA + fused stats): xpack(slotA) -> slotB ----
    conv1_mfma<<<1024, 256, 0, stream>>>(xpack, wprep1, slotB, fs0, fs0 + 512);
    bn_act16f<<<2048, 256, 0, stream>>>(slotB, fs0, fs0 + 512, g1, b1, 63,
                                        1.f/262144.f, 0.2f, (size_t)2097152);

    // ---- conv2 (COB=128/CO_FR=2): slotB -> slotA ----
    mfma_conv<64,32,32,16,16,128, 128,256,1,2,false,false><<<dim3(256,1,1), 256, 0, stream>>>(
        slotB, wprep, slotA, nullptr, 0, fs1, fs1 + 512);
    bn_act16f<<<2048, 256, 0, stream>>>(slotA, fs1, fs1 + 512, g2, b2, 127,
                                        1.f/65536.f, 0.2f, (size_t)1048576);

    // ---- conv3 (COB=64): slotA -> A_hi f16 ----
    mfma_conv<128,16,16,8,8,256, 64,256,1,1,false,false><<<dim3(64,4,1), 256, 0, stream>>>(
        slotA, wprep + 131072, A_hi, nullptr, 0, fs2, fs2 + 512);
    bn_act16f<<<2048, 256, 0, stream>>>(A_hi, fs2, fs2 + 512, g3, b3, 255,
                                        1.f/16384.f, 0.2f, (size_t)524288);

    // ---- conv4 (KS=4, COB=128/CO_FR=2): A_hi -> pB ----
    mfma_conv<256,8,8,4,4,512, 128,256,4,2,false,false><<<dim3(16,4,4), 256, 0, stream>>>(
        A_hi, wprep + 655360, nullptr, pB, (size_t)2097152, nullptr, nullptr);
    bn_partial<float,4><<<dim3(32,8), 256, 0, stream>>>(pB, (size_t)2097152, psum, psq, 512, 128, 32);
    bn_finalize<<<2, 256, 0, stream>>>(psum, psq, g4, b4, scale, shift, 512, 32, 1.f/4096.f);
    bn_act32<4><<<1024, 256, 0, stream>>>(pB, (size_t)2097152, slotA, scale, shift, 511, 0.2f);

    // ---- channel-wise linear: slotA(lo) -> slotB(lo) ----
    chanlin16<<<8192, 256, 0, stream>>>(slotA, cww, cwb, slotB);

    // ---- deconv1 (COB=64): slotB(lo) -> A_hi ----
    mfma_conv<512,4,4,8,8,256, 64,256,1,1,true,false><<<dim3(16,4,4), 256, 0, stream>>>(
        slotB, wprep + 2752512, A_hi, nullptr, 0, fs4, fs4 + 512);
    bn_act16f<<<2048, 256, 0, stream>>>(A_hi, fs4, fs4 + 512, dg1, db1, 255,
                                        1.f/16384.f, 0.f, (size_t)524288);

    // ---- deconv2 (COB=128/CO_FR=2): A_hi -> slotB(lo) ----
    mfma_conv<256,8,8,16,16,128, 128,256,1,2,true,false><<<dim3(64,1,4), 256, 0, stream>>>(
        A_hi, wprep + 4849664, slotB, nullptr, 0, fs5, fs5 + 512);
    bn_act16f<<<2048, 256, 0, stream>>>(slotB, fs5, fs5 + 512, dg2, db2, 127,
                                        1.f/65536.f, 0.f, (size_t)1048576);

    // ---- deconv3 (PW-FOLDED, round-24 verified): slotB(lo) -> slotA ----
    deconv3_pwf<<<dim3(256,2), 256, 0, stream>>>(
        slotB, wprep + 5373952, slotA, fs6, fs6 + 512);
    bn_act16f<<<2048, 256, 0, stream>>>(slotA, fs6, fs6 + 512, dg3, db3, 63,
                                        1.f/262144.f, 0.f, (size_t)2097152);

    // ---- deconv4 (MFMA, halo-staged) + tanh: slotA -> d_out ----
    deconv4_mfma<<<1024, 256, 0, stream>>>(slotA, wprep4, (float*)d_out);
}